// Round 2
// baseline (6424.377 us; speedup 1.0000x reference)
//
#include <hip/hip_runtime.h>
#include <math.h>

#define DEV static __device__ __forceinline__

DEV float4 ld4(const float* p){ return *(const float4*)p; }
DEV void   st4(float* p, float4 v){ *(float4*)p = v; }
DEV float4 f4add(float4 a, float4 b){ return make_float4(a.x+b.x,a.y+b.y,a.z+b.z,a.w+b.w); }
DEV float4 f4fma(float s, float4 a, float4 c){ return make_float4(fmaf(s,a.x,c.x),fmaf(s,a.y,c.y),fmaf(s,a.z,c.z),fmaf(s,a.w,c.w)); }
DEV float4 f4relu(float4 a){ return make_float4(fmaxf(a.x,0.f),fmaxf(a.y,0.f),fmaxf(a.z,0.f),fmaxf(a.w,0.f)); }

// ---------------- GNN: embedding tables  T[161][128] = emb_f @ W_slice ----------------
__global__ __launch_bounds__(128) void build_tables_k(
    const float* __restrict__ ea, const float* __restrict__ ed, const float* __restrict__ ec,
    const float* __restrict__ eh, const float* __restrict__ ear, const float* __restrict__ ech,
    const float* __restrict__ Wm, float* __restrict__ T)
{
    int r = blockIdx.x, c = threadIdx.x;
    const float* e; int dim, woff, rl;
    if      (r < 120) { e=ea;  dim=64; woff=0;   rl=r; }
    else if (r < 132) { e=ed;  dim=16; woff=64;  rl=r-120; }
    else if (r < 147) { e=ec;  dim=16; woff=80;  rl=r-132; }
    else if (r < 155) { e=eh;  dim=8;  woff=96;  rl=r-147; }
    else if (r < 157) { e=ear; dim=4;  woff=104; rl=r-155; }
    else              { e=ech; dim=4;  woff=108; rl=r-157; }
    float acc = 0.f;
    for (int k = 0; k < dim; ++k) acc += e[rl*dim + k] * Wm[(woff + k)*128 + c];
    T[r*128 + c] = acc;
}

// H[i][:] = sum of 6 table rows (+ charge * Wrow112)
__global__ __launch_bounds__(256) void embed_lookup_k(
    const int* __restrict__ xi, const float* __restrict__ charge,
    const float* __restrict__ T, const float* __restrict__ wq,
    float* __restrict__ H, int N)
{
    int t = threadIdx.x;
    int node = blockIdx.x*8 + (t >> 5);
    if (node >= N) return;
    int c = (t & 31)*4;
    const int* xp = xi + node*6;
    float4 acc = ld4(T + (       xp[0])*128 + c);
    acc = f4add(acc, ld4(T + (120+xp[1])*128 + c));
    acc = f4add(acc, ld4(T + (132+xp[2])*128 + c));
    acc = f4add(acc, ld4(T + (147+xp[3])*128 + c));
    acc = f4add(acc, ld4(T + (155+xp[4])*128 + c));
    acc = f4add(acc, ld4(T + (157+xp[5])*128 + c));
    if (charge) acc = f4fma(charge[node], ld4(wq + c), acc);
    st4(H + (size_t)node*128 + c, acc);
}

// ---------------- GCN degree / norm ----------------
__global__ void init_deg_k(float* deg, int N){ int i = blockIdx.x*256+threadIdx.x; if (i<N) deg[i]=1.f; }

__global__ void deg_scatter_k(const int* __restrict__ col, const float* __restrict__ ew, float* deg, int E){
    int e = blockIdx.x*256+threadIdx.x; if (e>=E) return;
    unsafeAtomicAdd(deg + col[e], ew ? ew[e] : 1.f);
}

__global__ void dis_k(const float* __restrict__ deg, float* __restrict__ dis, int N){
    int i = blockIdx.x*256+threadIdx.x; if (i<N) dis[i] = 1.f/sqrtf(deg[i]);
}

__global__ void norm_k(const int* __restrict__ row, const int* __restrict__ col,
                       const float* __restrict__ ew, const float* __restrict__ dis,
                       float* __restrict__ nrm, int E){
    int e = blockIdx.x*256+threadIdx.x; if (e>=E) return;
    float w = ew ? ew[e] : 1.f;
    nrm[e] = dis[row[e]] * w * dis[col[e]];
}

// O[i][j] = H[i][j]*dis[i]^2 + b[j]   (self loop + bias = scatter init)
__global__ __launch_bounds__(256) void self_init_k(
    const float* __restrict__ H, const float* __restrict__ dis,
    const float* __restrict__ bias, float* __restrict__ O, int N)
{
    int idx = blockIdx.x*256 + threadIdx.x;          // over N*32 float4s
    int i = idx >> 5, j4 = (idx & 31)*4;
    if (i >= N) return;
    float s = dis[i]; s *= s;
    float4 h = ld4(H + (size_t)i*128 + j4);
    float4 b = ld4(bias + j4);
    st4(O + (size_t)i*128 + j4, f4fma(s, h, b));
}

// O[col[e]][:] += H[row[e]][:] * nrm[e]   (64 lanes/edge, float2 each)
__global__ __launch_bounds__(256) void gcn_scatter_k(
    const float* __restrict__ H, const int* __restrict__ row, const int* __restrict__ col,
    const float* __restrict__ nrm, float* __restrict__ O, int E)
{
    int e = blockIdx.x*4 + (threadIdx.x >> 6);
    if (e >= E) return;
    int lane = threadIdx.x & 63;
    int rs = row[e], cs = col[e];
    float nm = nrm[e];
    float2 hv = *(const float2*)(H + (size_t)rs*128 + lane*2);
    float* op = O + (size_t)cs*128 + lane*2;
    unsafeAtomicAdd(op,     hv.x*nm);
    unsafeAtomicAdd(op + 1, hv.y*nm);
}

// O = relu(A) @ W ; A:[N,128] W:[128,128]
__global__ __launch_bounds__(256) void gemm_relu128_k(
    const float* __restrict__ A, const float* __restrict__ W, float* __restrict__ O, int N)
{
    __shared__ float As[128*128];
    int t = threadIdx.x;
    int row0 = blockIdx.x * 128;
    int r = t >> 1, c0 = (t & 1)*64;
    for (int i = 0; i < 16; ++i) {
        float4 v = ld4(A + (size_t)(row0 + r)*128 + c0 + i*4);
        st4(As + r*128 + c0 + i*4, f4relu(v));
    }
    __syncthreads();
    int rg = (t >> 5)*16;
    int c  = (t & 31)*4;
    float4 acc[16];
    for (int i = 0; i < 16; ++i) acc[i] = make_float4(0.f,0.f,0.f,0.f);
    for (int k = 0; k < 128; ++k) {
        float4 w = ld4(W + k*128 + c);
        #pragma unroll
        for (int rr = 0; rr < 16; ++rr) {
            float a = As[(rg + rr)*128 + k];
            acc[rr] = f4fma(a, w, acc[rr]);
        }
    }
    for (int rr = 0; rr < 16; ++rr)
        st4(O + (size_t)(row0 + rg + rr)*128 + c, acc[rr]);
}

// ---------------- mean pool (batch_vec sorted -> register run-length accumulate) ----------------
__global__ __launch_bounds__(128) void mean_pool_sum_k(
    const float* __restrict__ X, const int* __restrict__ bv,
    float* __restrict__ featp /* stride 512 */, int chunk, int N)
{
    __shared__ float acc[16*128];
    int t = threadIdx.x;
    for (int b = 0; b < 16; ++b) acc[b*128 + t] = 0.f;
    int i0 = blockIdx.x * chunk;
    int iend = min(i0 + chunk, N);
    int bcur = bv[i0];
    float r = 0.f;
    for (int i = i0; i < iend; ++i) {
        int b = bv[i];
        if (b != bcur) { acc[bcur*128 + t] += r; r = 0.f; bcur = b; }
        r += fmaxf(X[(size_t)i*128 + t], 0.f);
    }
    acc[bcur*128 + t] += r;
    for (int b = 0; b < 16; ++b) {
        float v = acc[b*128 + t];
        if (v != 0.f) unsafeAtomicAdd(featp + b*512 + t, v);
    }
}

__global__ void count_batch_k(const int* __restrict__ bv, float* __restrict__ cnt, int N){
    __shared__ int h[16];
    int t = threadIdx.x;
    if (t < 16) h[t] = 0;
    __syncthreads();
    int i = blockIdx.x*256 + t;
    if (i < N) atomicAdd(&h[bv[i]], 1);
    __syncthreads();
    if (t < 16 && h[t]) unsafeAtomicAdd(&cnt[t], (float)h[t]);
}

// ---------------- voxel CNN ----------------
// direct conv 3x3x3 SAME, 4 outputs along w per thread; fused bias + BN-stat partials
// out may be nullptr (stats-only pass)
__global__ __launch_bounds__(256) void conv3d_k(
    const float* __restrict__ in, const float* __restrict__ wt, const float* __restrict__ bias,
    float* __restrict__ out, float* __restrict__ stats, int Cin, int D, int Cout)
{
    int t  = threadIdx.x;
    int sp = blockIdx.x*256 + t;
    int W4 = D >> 2;
    int w0 = (sp % W4)*4;
    int h  = (sp / W4) % D;
    int d  = sp / (W4*D);
    int n  = blockIdx.y / Cout, co = blockIdx.y % Cout;
    int DD = D*D, DDD = DD*D;
    const float* wb  = wt + co*Cin*27;
    const float* inb = in + (size_t)n*Cin*DDD;
    float a0=0.f, a1=0.f, a2=0.f, a3=0.f;
    for (int ci = 0; ci < Cin; ++ci) {
        const float* ib = inb + (size_t)ci*DDD;
        const float* wc = wb + ci*27;
        for (int kd = 0; kd < 3; ++kd) {
            int z = d + kd - 1; if ((unsigned)z >= (unsigned)D) continue;
            for (int kh = 0; kh < 3; ++kh) {
                int y = h + kh - 1; if ((unsigned)y >= (unsigned)D) continue;
                const float* rp = ib + (size_t)(z*D + y)*D;
                float wA = wc[kd*9 + kh*3 + 0], wB = wc[kd*9 + kh*3 + 1], wC = wc[kd*9 + kh*3 + 2];
                float vm1 = (w0 > 0)      ? rp[w0-1] : 0.f;
                float v0 = rp[w0], v1 = rp[w0+1], v2 = rp[w0+2], v3 = rp[w0+3];
                float v4 = (w0+4 < D)     ? rp[w0+4] : 0.f;
                a0 = fmaf(wA,vm1, fmaf(wB,v0, fmaf(wC,v1, a0)));
                a1 = fmaf(wA,v0,  fmaf(wB,v1, fmaf(wC,v2, a1)));
                a2 = fmaf(wA,v1,  fmaf(wB,v2, fmaf(wC,v3, a2)));
                a3 = fmaf(wA,v2,  fmaf(wB,v3, fmaf(wC,v4, a3)));
            }
        }
    }
    float bb = bias[co];
    a0 += bb; a1 += bb; a2 += bb; a3 += bb;
    if (out) {
        float* op = out + (size_t)blockIdx.y*DDD + (size_t)(d*D + h)*D + w0;
        op[0]=a0; op[1]=a1; op[2]=a2; op[3]=a3;
    }
    // BN partial sums (whole block shares co)
    float s  = a0+a1+a2+a3;
    float s2 = a0*a0 + a1*a1 + a2*a2 + a3*a3;
    __shared__ float rs[256], rq[256];
    rs[t]=s; rq[t]=s2;
    __syncthreads();
    for (int off = 128; off; off >>= 1) {
        if (t < off) { rs[t] += rs[t+off]; rq[t] += rq[t+off]; }
        __syncthreads();
    }
    if (t == 0) {
        unsafeAtomicAdd(&stats[co*2],     rs[0]);
        unsafeAtomicAdd(&stats[co*2 + 1], rq[0]);
    }
}

__global__ void bn_final_k(const float* __restrict__ stats, const float* __restrict__ g,
                           const float* __restrict__ b, float* __restrict__ sc, float* __restrict__ sh,
                           int C, float invN)
{
    int c = threadIdx.x; if (c >= C) return;
    float m = stats[c*2] * invN;
    float v = stats[c*2+1] * invN - m*m;
    float s = g[c] * rsqrtf(v + 1e-5f);
    sc[c] = s; sh[c] = b[c] - m*s;
}

// conv1 recompute fused with BN+relu+pool: one pooled output per thread (2x2x2 conv outputs)
__global__ __launch_bounds__(256) void conv_bn_pool1_k(
    const float* __restrict__ in, const float* __restrict__ wt, const float* __restrict__ bias,
    const float* __restrict__ sc, const float* __restrict__ sh, float* __restrict__ out)
{
    int idx = blockIdx.x*256 + threadIdx.x;   // [16n][16c][32][32][32]
    int ow = idx & 31; int t = idx >> 5;
    int oh = t & 31; t >>= 5;
    int od = t & 31; t >>= 5;
    int co = t & 15; int n = t >> 4;
    const int D = 64, DDD = 262144;
    float acc[2][2][2] = {};
    const float* inb = in + (size_t)n*2*DDD;
    const float* wb  = wt + co*2*27;
    for (int ci = 0; ci < 2; ++ci) {
        const float* ib = inb + (size_t)ci*DDD;
        const float* wc = wb + ci*27;
        float v[4][4][4];
        #pragma unroll
        for (int a = 0; a < 4; ++a) {
            int z = od*2 - 1 + a; bool zok = (unsigned)z < 64u;
            #pragma unroll
            for (int b = 0; b < 4; ++b) {
                int y = oh*2 - 1 + b; bool yok = zok && ((unsigned)y < 64u);
                #pragma unroll
                for (int c = 0; c < 4; ++c) {
                    int x = ow*2 - 1 + c;
                    v[a][b][c] = (yok && (unsigned)x < 64u) ? ib[((size_t)z*D + y)*D + x] : 0.f;
                }
            }
        }
        #pragma unroll
        for (int kd = 0; kd < 3; ++kd)
        #pragma unroll
        for (int kh = 0; kh < 3; ++kh)
        #pragma unroll
        for (int kw = 0; kw < 3; ++kw) {
            float w = wc[kd*9 + kh*3 + kw];
            #pragma unroll
            for (int dz = 0; dz < 2; ++dz)
            #pragma unroll
            for (int dy = 0; dy < 2; ++dy)
            #pragma unroll
            for (int dx = 0; dx < 2; ++dx)
                acc[dz][dy][dx] = fmaf(w, v[dz+kd][dy+kh][dx+kw], acc[dz][dy][dx]);
        }
    }
    float cb = bias[co], s = sc[co], bb = sh[co];
    float m = 0.f;
    #pragma unroll
    for (int dz = 0; dz < 2; ++dz)
    #pragma unroll
    for (int dy = 0; dy < 2; ++dy)
    #pragma unroll
    for (int dx = 0; dx < 2; ++dx)
        m = fmaxf(m, fmaf(acc[dz][dy][dx] + cb, s, bb));
    out[idx] = m;   // relu folded: m starts at 0
}

__global__ __launch_bounds__(256) void bn_relu_pool_k(
    const float* __restrict__ y, const float* __restrict__ sc, const float* __restrict__ sh,
    float* __restrict__ o, int C, int Din)
{
    int Do = Din >> 1;
    int idx = blockIdx.x*256 + threadIdx.x;
    int ow = idx % Do; int tmp = idx / Do;
    int oh = tmp % Do; tmp /= Do;
    int od = tmp % Do; int nc = tmp / Do;
    int c = nc % C;
    float s = sc[c], bb = sh[c];
    const float* yb = y + (size_t)nc*Din*Din*Din;
    float m = 0.f;
    for (int dz = 0; dz < 2; ++dz)
        for (int dy = 0; dy < 2; ++dy)
            for (int dx = 0; dx < 2; ++dx) {
                float v = yb[(size_t)((od*2+dz)*Din + oh*2+dy)*Din + ow*2+dx];
                m = fmaxf(m, fmaxf(fmaf(v, s, bb), 0.f));
            }
    o[idx] = m;
}

// fc: X[16,32768] @ W[32768,128] -> accumulate into feat[:,384:512]
__global__ __launch_bounds__(128) void fc_acc_k(
    const float* __restrict__ X, const float* __restrict__ W, float* __restrict__ featv)
{
    int t = threadIdx.x;
    int k0 = blockIdx.x*256;
    float acc[16];
    #pragma unroll
    for (int b = 0; b < 16; ++b) acc[b] = 0.f;
    for (int k = k0; k < k0 + 256; ++k) {
        float w = W[(size_t)k*128 + t];
        #pragma unroll
        for (int b = 0; b < 16; ++b) acc[b] = fmaf(X[(size_t)b*32768 + k], w, acc[b]);
    }
    for (int b = 0; b < 16; ++b) unsafeAtomicAdd(featv + b*512 + t, acc[b]);
}

// ---------------- small dense layers ----------------
__global__ __launch_bounds__(256) void head_k(
    const float* __restrict__ X, const float* __restrict__ W, const float* __restrict__ b,
    float* __restrict__ O, int K, int Ncol, int relu)
{
    int t = blockIdx.x*256 + threadIdx.x;
    if (t >= 16*Ncol) return;
    int bi = t / Ncol, c = t % Ncol;
    float acc = b[c];
    for (int k = 0; k < K; ++k) acc = fmaf(X[bi*K + k], W[k*Ncol + c], acc);
    if (relu) acc = fmaxf(acc, 0.f);
    O[bi*Ncol + c] = acc;
}

__global__ void gebn_k(const float* __restrict__ g2, const float* __restrict__ g,
                       const float* __restrict__ b, float* __restrict__ featg /* stride 512 */)
{
    int c = threadIdx.x;  // 128
    float m = 0.f;
    for (int i = 0; i < 16; ++i) m += g2[i*128 + c];
    m *= (1.f/16.f);
    float v = 0.f;
    for (int i = 0; i < 16; ++i) { float d = g2[i*128 + c] - m; v += d*d; }
    v *= (1.f/16.f);
    float s = g[c] * rsqrtf(v + 1e-5f);
    for (int i = 0; i < 16; ++i)
        featg[i*512 + c] = fmaxf((g2[i*128 + c] - m)*s + b[c], 0.f);
}

__global__ void finalize_feat_k(float* __restrict__ feat, const float* __restrict__ cntm,
                                const float* __restrict__ cntz, const float* __restrict__ fcb)
{
    int t = blockIdx.x*256 + threadIdx.x;   // 16*512
    if (t >= 8192) return;
    int bi = t >> 9, c = t & 511;
    float v = feat[t];
    if      (c < 128) v /= fmaxf(cntm[bi], 1.f);
    else if (c < 256) v /= fmaxf(cntz[bi], 1.f);
    else if (c >= 384) v = fmaxf(v + fcb[c - 384], 0.f);
    feat[t] = v;
}

// =====================================================================================
extern "C" void kernel_launch(void* const* d_in, const int* in_sizes, int n_in,
                              void* d_out, int out_size, void* d_ws, size_t ws_size,
                              hipStream_t stream)
{
    const int*   mol_x  = (const int*)  d_in[0];
    const float* mol_q  = (const float*)d_in[1];
    const int*   mol_ei = (const int*)  d_in[2];
    const float* mol_ew = (const float*)d_in[3];
    const int*   mol_bv = (const int*)  d_in[4];
    const int*   zeo_x  = (const int*)  d_in[5];
    const int*   zeo_ei = (const int*)  d_in[6];
    const int*   zeo_bv = (const int*)  d_in[7];
    const float* voxel  = (const float*)d_in[8];
    const float* gattr  = (const float*)d_in[9];
    const float* ea  = (const float*)d_in[10];
    const float* ed  = (const float*)d_in[11];
    const float* ec  = (const float*)d_in[12];
    const float* eh  = (const float*)d_in[13];
    const float* ear = (const float*)d_in[14];
    const float* ech = (const float*)d_in[15];
    const float* mc1w=(const float*)d_in[16]; const float* mc1b=(const float*)d_in[17];
    const float* mc2w=(const float*)d_in[18]; const float* mc2b=(const float*)d_in[19];
    const float* zc1w=(const float*)d_in[20]; const float* zc1b=(const float*)d_in[21];
    const float* zc2w=(const float*)d_in[22]; const float* zc2b=(const float*)d_in[23];
    const float* cv1w=(const float*)d_in[24]; const float* cv1b=(const float*)d_in[25];
    const float* bn1g=(const float*)d_in[26]; const float* bn1b=(const float*)d_in[27];
    const float* cv2w=(const float*)d_in[28]; const float* cv2b=(const float*)d_in[29];
    const float* bn2g=(const float*)d_in[30]; const float* bn2b=(const float*)d_in[31];
    const float* cv3w=(const float*)d_in[32]; const float* cv3b=(const float*)d_in[33];
    const float* bn3g=(const float*)d_in[34]; const float* bn3b=(const float*)d_in[35];
    const float* fcw =(const float*)d_in[36]; const float* fcb =(const float*)d_in[37];
    const float* ge1w=(const float*)d_in[38]; const float* ge1b=(const float*)d_in[39];
    const float* ge2w=(const float*)d_in[40]; const float* ge2b=(const float*)d_in[41];
    const float* gbng=(const float*)d_in[42]; const float* gbnb=(const float*)d_in[43];
    const float* h1w =(const float*)d_in[44]; const float* h1b =(const float*)d_in[45];
    const float* h2w =(const float*)d_in[46]; const float* h2b =(const float*)d_in[47];
    const float* h3w =(const float*)d_in[48]; const float* h3b =(const float*)d_in[49];

    const int Nm = in_sizes[0]/6, Em = in_sizes[2]/2;
    const int Nz = in_sizes[5]/6, Ez = in_sizes[6]/2;

    float* WS = (float*)d_ws;
    float* A  = WS;                     // 16,777,216 floats (67 MB)
    float* Bb = WS + 16777216;          // 16,777,216 floats (67 MB)
    float* S  = WS + 33554432;          // small scratch
    float* deg  = S;
    float* dis  = S + 131072;
    float* nrm  = S + 262144;
    float* T    = S + 786432;           // 161*128
    float* cntm = S + 807040;
    float* cntz = S + 807056;
    float* feat = S + 807072;           // [16][512]
    float* st1  = S + 815264; float* st2 = st1 + 32; float* st3 = st1 + 96;
    float* sc1  = S + 815488; float* sh1 = sc1 + 16;
    float* sc2  = sc1 + 32;   float* sh2 = sc1 + 64;
    float* sc3  = sc1 + 96;   float* sh3 = sc1 + 160;
    float* g1   = S + 815712;           // 16*64
    float* g2   = S + 816736;           // 16*128
    float* H1   = S + 818784;           // 16*512
    float* H2   = S + 826976;           // 16*256

    // zero all small accumulators (graph re-zeroes each replay)
    hipMemsetAsync(S, 0, (size_t)831072*sizeof(float), stream);

    // ---------------- molecule branch ----------------
    build_tables_k<<<161,128,0,stream>>>(ea,ed,ec,eh,ear,ech, mc1w, T);
    init_deg_k   <<<Nm/256,256,0,stream>>>(deg, Nm);
    deg_scatter_k<<<Em/256,256,0,stream>>>(mol_ei+Em, mol_ew, deg, Em);
    dis_k        <<<Nm/256,256,0,stream>>>(deg, dis, Nm);
    norm_k       <<<Em/256,256,0,stream>>>(mol_ei, mol_ei+Em, mol_ew, dis, nrm, Em);
    embed_lookup_k<<<Nm/8,256,0,stream>>>(mol_x, mol_q, T, mc1w + 112*128, A, Nm);
    self_init_k  <<<Nm/8,256,0,stream>>>(A, dis, mc1b, Bb, Nm);
    gcn_scatter_k<<<Em/4,256,0,stream>>>(A, mol_ei, mol_ei+Em, nrm, Bb, Em);
    gemm_relu128_k<<<Nm/128,256,0,stream>>>(Bb, mc2w, A, Nm);
    self_init_k  <<<Nm/8,256,0,stream>>>(A, dis, mc2b, Bb, Nm);
    gcn_scatter_k<<<Em/4,256,0,stream>>>(A, mol_ei, mol_ei+Em, nrm, Bb, Em);
    count_batch_k<<<Nm/256,256,0,stream>>>(mol_bv, cntm, Nm);
    mean_pool_sum_k<<<256,128,0,stream>>>(Bb, mol_bv, feat + 0, (Nm+255)/256, Nm);

    // ---------------- zeolite branch ----------------
    build_tables_k<<<161,128,0,stream>>>(ea,ed,ec,eh,ear,ech, zc1w, T);
    init_deg_k   <<<Nz/256,256,0,stream>>>(deg, Nz);
    deg_scatter_k<<<Ez/256,256,0,stream>>>(zeo_ei+Ez, nullptr, deg, Ez);
    dis_k        <<<Nz/256,256,0,stream>>>(deg, dis, Nz);
    norm_k       <<<Ez/256,256,0,stream>>>(zeo_ei, zeo_ei+Ez, nullptr, dis, nrm, Ez);
    embed_lookup_k<<<Nz/8,256,0,stream>>>(zeo_x, nullptr, T, nullptr, A, Nz);
    self_init_k  <<<Nz/8,256,0,stream>>>(A, dis, zc1b, Bb, Nz);
    gcn_scatter_k<<<Ez/4,256,0,stream>>>(A, zeo_ei, zeo_ei+Ez, nrm, Bb, Ez);
    gemm_relu128_k<<<Nz/128,256,0,stream>>>(Bb, zc2w, A, Nz);
    self_init_k  <<<Nz/8,256,0,stream>>>(A, dis, zc2b, Bb, Nz);
    gcn_scatter_k<<<Ez/4,256,0,stream>>>(A, zeo_ei, zeo_ei+Ez, nrm, Bb, Ez);
    count_batch_k<<<Nz/256,256,0,stream>>>(zeo_bv, cntz, Nz);
    mean_pool_sum_k<<<256,128,0,stream>>>(Bb, zeo_bv, feat + 128, (Nz+255)/256, Nz);

    // ---------------- voxel CNN ----------------
    // layer 1: stats-only conv pass, then fused conv+bn+relu+pool (no 268MB buffer)
    conv3d_k<<<dim3(256, 16*16),256,0,stream>>>(voxel, cv1w, cv1b, nullptr, st1, 2, 64, 16);
    bn_final_k<<<1,64,0,stream>>>(st1, bn1g, bn1b, sc1, sh1, 16, 1.f/(16.f*262144.f));
    conv_bn_pool1_k<<<32768,256,0,stream>>>(voxel, cv1w, cv1b, sc1, sh1, Bb);  // Bb: [16][16][32^3]

    conv3d_k<<<dim3(32, 16*32),256,0,stream>>>(Bb, cv2w, cv2b, A, st2, 16, 32, 32);
    bn_final_k<<<1,64,0,stream>>>(st2, bn2g, bn2b, sc2, sh2, 32, 1.f/(16.f*32768.f));
    bn_relu_pool_k<<<(16*32*4096)/256,256,0,stream>>>(A, sc2, sh2, Bb, 32, 32);

    conv3d_k<<<dim3(4, 16*64),256,0,stream>>>(Bb, cv3w, cv3b, A, st3, 32, 16, 64);
    bn_final_k<<<1,64,0,stream>>>(st3, bn3g, bn3b, sc3, sh3, 64, 1.f/(16.f*4096.f));
    bn_relu_pool_k<<<(16*64*512)/256,256,0,stream>>>(A, sc3, sh3, Bb, 64, 16);

    fc_acc_k<<<128,128,0,stream>>>(Bb, fcw, feat + 384);

    // ---------------- global encoder ----------------
    head_k<<<4,256,0,stream>>>(gattr, ge1w, ge1b, g1, 17, 64, 1);
    head_k<<<8,256,0,stream>>>(g1, ge2w, ge2b, g2, 64, 128, 0);
    gebn_k<<<1,128,0,stream>>>(g2, gbng, gbnb, feat + 256);

    // ---------------- fusion head ----------------
    finalize_feat_k<<<32,256,0,stream>>>(feat, cntm, cntz, fcb);
    head_k<<<32,256,0,stream>>>(feat, h1w, h1b, H1, 512, 512, 1);
    head_k<<<16,256,0,stream>>>(H1, h2w, h2b, H2, 512, 256, 1);
    head_k<<<1,256,0,stream>>>(H2, h3w, h3b, (float*)d_out, 256, 3, 0);
}

// Round 3
// 3501.905 us; speedup vs baseline: 1.8345x; 1.8345x over previous
//
#include <hip/hip_runtime.h>
#include <math.h>

#define DEV static __device__ __forceinline__

DEV float4 ld4(const float* p){ return *(const float4*)p; }
DEV void   st4(float* p, float4 v){ *(float4*)p = v; }
DEV float4 f4add(float4 a, float4 b){ return make_float4(a.x+b.x,a.y+b.y,a.z+b.z,a.w+b.w); }
DEV float4 f4fma(float s, float4 a, float4 c){ return make_float4(fmaf(s,a.x,c.x),fmaf(s,a.y,c.y),fmaf(s,a.z,c.z),fmaf(s,a.w,c.w)); }
DEV float4 f4relu(float4 a){ return make_float4(fmaxf(a.x,0.f),fmaxf(a.y,0.f),fmaxf(a.z,0.f),fmaxf(a.w,0.f)); }

// ---------------- GNN: embedding tables  T[161][128] = emb_f @ W_slice ----------------
__global__ __launch_bounds__(128) void build_tables_k(
    const float* __restrict__ ea, const float* __restrict__ ed, const float* __restrict__ ec,
    const float* __restrict__ eh, const float* __restrict__ ear, const float* __restrict__ ech,
    const float* __restrict__ Wm, float* __restrict__ T)
{
    int r = blockIdx.x, c = threadIdx.x;
    const float* e; int dim, woff, rl;
    if      (r < 120) { e=ea;  dim=64; woff=0;   rl=r; }
    else if (r < 132) { e=ed;  dim=16; woff=64;  rl=r-120; }
    else if (r < 147) { e=ec;  dim=16; woff=80;  rl=r-132; }
    else if (r < 155) { e=eh;  dim=8;  woff=96;  rl=r-147; }
    else if (r < 157) { e=ear; dim=4;  woff=104; rl=r-155; }
    else              { e=ech; dim=4;  woff=108; rl=r-157; }
    float acc = 0.f;
    for (int k = 0; k < dim; ++k) acc += e[rl*dim + k] * Wm[(woff + k)*128 + c];
    T[r*128 + c] = acc;
}

// H[i][:] = sum of 6 table rows (+ charge * Wrow112)
__global__ __launch_bounds__(256) void embed_lookup_k(
    const int* __restrict__ xi, const float* __restrict__ charge,
    const float* __restrict__ T, const float* __restrict__ wq,
    float* __restrict__ H, int N)
{
    int t = threadIdx.x;
    int node = blockIdx.x*8 + (t >> 5);
    if (node >= N) return;
    int c = (t & 31)*4;
    const int* xp = xi + node*6;
    float4 acc = ld4(T + (       xp[0])*128 + c);
    acc = f4add(acc, ld4(T + (120+xp[1])*128 + c));
    acc = f4add(acc, ld4(T + (132+xp[2])*128 + c));
    acc = f4add(acc, ld4(T + (147+xp[3])*128 + c));
    acc = f4add(acc, ld4(T + (155+xp[4])*128 + c));
    acc = f4add(acc, ld4(T + (157+xp[5])*128 + c));
    if (charge) acc = f4fma(charge[node], ld4(wq + c), acc);
    st4(H + (size_t)node*128 + c, acc);
}

// ---------------- GCN degree / norm ----------------
__global__ void init_deg_k(float* deg, int N){ int i = blockIdx.x*256+threadIdx.x; if (i<N) deg[i]=1.f; }

__global__ void deg_scatter_k(const int* __restrict__ col, const float* __restrict__ ew, float* deg, int E){
    int e = blockIdx.x*256+threadIdx.x; if (e>=E) return;
    unsafeAtomicAdd(deg + col[e], ew ? ew[e] : 1.f);
}

__global__ void dis_k(const float* __restrict__ deg, float* __restrict__ dis, int N){
    int i = blockIdx.x*256+threadIdx.x; if (i<N) dis[i] = 1.f/sqrtf(deg[i]);
}

__global__ void norm_k(const int* __restrict__ row, const int* __restrict__ col,
                       const float* __restrict__ ew, const float* __restrict__ dis,
                       float* __restrict__ nrm, int E){
    int e = blockIdx.x*256+threadIdx.x; if (e>=E) return;
    float w = ew ? ew[e] : 1.f;
    nrm[e] = dis[row[e]] * w * dis[col[e]];
}

// O[i][j] = H[i][j]*dis[i]^2 + b[j]   (self loop + bias = scatter init)
__global__ __launch_bounds__(256) void self_init_k(
    const float* __restrict__ H, const float* __restrict__ dis,
    const float* __restrict__ bias, float* __restrict__ O, int N)
{
    int idx = blockIdx.x*256 + threadIdx.x;          // over N*32 float4s
    int i = idx >> 5, j4 = (idx & 31)*4;
    if (i >= N) return;
    float s = dis[i]; s *= s;
    float4 h = ld4(H + (size_t)i*128 + j4);
    float4 b = ld4(bias + j4);
    st4(O + (size_t)i*128 + j4, f4fma(s, h, b));
}

// O[col[e]][:] += H[row[e]][:] * nrm[e]   (64 lanes/edge, float2 each)
__global__ __launch_bounds__(256) void gcn_scatter_k(
    const float* __restrict__ H, const int* __restrict__ row, const int* __restrict__ col,
    const float* __restrict__ nrm, float* __restrict__ O, int E)
{
    int e = blockIdx.x*4 + (threadIdx.x >> 6);
    if (e >= E) return;
    int lane = threadIdx.x & 63;
    int rs = row[e], cs = col[e];
    float nm = nrm[e];
    float2 hv = *(const float2*)(H + (size_t)rs*128 + lane*2);
    float* op = O + (size_t)cs*128 + lane*2;
    unsafeAtomicAdd(op,     hv.x*nm);
    unsafeAtomicAdd(op + 1, hv.y*nm);
}

// O = relu(A) @ W ; A:[N,128] W:[128,128]
__global__ __launch_bounds__(256) void gemm_relu128_k(
    const float* __restrict__ A, const float* __restrict__ W, float* __restrict__ O, int N)
{
    __shared__ float As[128*128];
    int t = threadIdx.x;
    int row0 = blockIdx.x * 128;
    int r = t >> 1, c0 = (t & 1)*64;
    for (int i = 0; i < 16; ++i) {
        float4 v = ld4(A + (size_t)(row0 + r)*128 + c0 + i*4);
        st4(As + r*128 + c0 + i*4, f4relu(v));
    }
    __syncthreads();
    int rg = (t >> 5)*16;
    int c  = (t & 31)*4;
    float4 acc[16];
    for (int i = 0; i < 16; ++i) acc[i] = make_float4(0.f,0.f,0.f,0.f);
    for (int k = 0; k < 128; ++k) {
        float4 w = ld4(W + k*128 + c);
        #pragma unroll
        for (int rr = 0; rr < 16; ++rr) {
            float a = As[(rg + rr)*128 + k];
            acc[rr] = f4fma(a, w, acc[rr]);
        }
    }
    for (int rr = 0; rr < 16; ++rr)
        st4(O + (size_t)(row0 + rg + rr)*128 + c, acc[rr]);
}

// ---------------- mean pool (batch_vec sorted -> register run-length accumulate) ----------------
__global__ __launch_bounds__(128) void mean_pool_sum_k(
    const float* __restrict__ X, const int* __restrict__ bv,
    float* __restrict__ featp /* stride 512 */, int chunk, int N)
{
    __shared__ float acc[16*128];
    int t = threadIdx.x;
    for (int b = 0; b < 16; ++b) acc[b*128 + t] = 0.f;
    int i0 = blockIdx.x * chunk;
    int iend = min(i0 + chunk, N);
    int bcur = bv[i0];
    float r = 0.f;
    for (int i = i0; i < iend; ++i) {
        int b = bv[i];
        if (b != bcur) { acc[bcur*128 + t] += r; r = 0.f; bcur = b; }
        r += fmaxf(X[(size_t)i*128 + t], 0.f);
    }
    acc[bcur*128 + t] += r;
    for (int b = 0; b < 16; ++b) {
        float v = acc[b*128 + t];
        if (v != 0.f) unsafeAtomicAdd(featp + b*512 + t, v);
    }
}

__global__ void count_batch_k(const int* __restrict__ bv, float* __restrict__ cnt, int N){
    __shared__ int h[16];
    int t = threadIdx.x;
    if (t < 16) h[t] = 0;
    __syncthreads();
    int i = blockIdx.x*256 + t;
    if (i < N) atomicAdd(&h[bv[i]], 1);
    __syncthreads();
    if (t < 16 && h[t]) unsafeAtomicAdd(&cnt[t], (float)h[t]);
}

// ---------------- voxel CNN: fused conv(3x3x3 SAME) + bias + BN-stats + maxpool/minpool ----------------
// One thread: 2x2x2 output block x 8 output channels. Weights packed in LDS as
// [ci][r=kd*3+kh][cl][kw(pad4)] -> one ds_read_b128 per 24 FMAs (broadcast).
// Writes pooled MAX and MIN (min covers BN scale<0 exactly); stats over full-res conv output.
template<int CIN, int COUT, int D>
__global__ __launch_bounds__(256) void conv_pool_k(
    const float* __restrict__ in, const float* __restrict__ wt, const float* __restrict__ bias,
    float* __restrict__ outmax, float* __restrict__ outmin, float* __restrict__ stats)
{
    constexpr int PD = D/2;
    constexpr int LG = (PD == 32) ? 5 : (PD == 16 ? 4 : 3);
    __shared__ float ldsW[CIN*9*32];
    __shared__ float swred[4*16];

    int tid = threadIdx.x;
    int co0 = blockIdx.y * 8;

    // stage packed weights
    for (int i = tid; i < CIN*9*32; i += 256) {
        int kw = i & 3, cl = (i >> 2) & 7, r = (i >> 5) % 9, ci = i / 288;
        ldsW[i] = (kw < 3) ? wt[((co0 + cl)*CIN + ci)*27 + r*3 + kw] : 0.f;
    }
    __syncthreads();

    int idx = blockIdx.x*256 + tid;
    int ow = idx & (PD-1);
    int oh = (idx >> LG) & (PD-1);
    int od = (idx >> (2*LG)) & (PD-1);
    int n  = idx >> (3*LG);

    float acc[8][8];
    #pragma unroll
    for (int cl = 0; cl < 8; ++cl)
        #pragma unroll
        for (int p = 0; p < 8; ++p) acc[cl][p] = 0.f;

    int z0 = (od << 1) - 1, y0 = (oh << 1) - 1, x0 = (ow << 1) - 1;

    for (int ci = 0; ci < CIN; ++ci) {
        const float* ib = in + ((size_t)n*CIN + ci)*((size_t)D*D*D);
        float v[4][4][4];
        #pragma unroll
        for (int a = 0; a < 4; ++a) {
            int z = z0 + a; bool zok = (unsigned)z < (unsigned)D;
            #pragma unroll
            for (int b = 0; b < 4; ++b) {
                int y = y0 + b; bool yok = zok && ((unsigned)y < (unsigned)D);
                const float* rp = ib + ((size_t)z*D + y)*D;
                #pragma unroll
                for (int c = 0; c < 4; ++c) {
                    int x = x0 + c;
                    v[a][b][c] = (yok && (unsigned)x < (unsigned)D) ? rp[x] : 0.f;
                }
            }
        }
        const float4* wrow = (const float4*)ldsW + ci*9*8;
        #pragma unroll
        for (int r = 0; r < 9; ++r) {
            const int kd = r/3, kh = r%3;
            #pragma unroll
            for (int cl = 0; cl < 8; ++cl) {
                float4 w = wrow[r*8 + cl];
                #pragma unroll
                for (int dz = 0; dz < 2; ++dz)
                #pragma unroll
                for (int dy = 0; dy < 2; ++dy)
                #pragma unroll
                for (int dx = 0; dx < 2; ++dx) {
                    float s = fmaf(w.x, v[dz+kd][dy+kh][dx],
                              fmaf(w.y, v[dz+kd][dy+kh][dx+1],
                                   w.z * v[dz+kd][dy+kh][dx+2]));
                    acc[cl][dz*4 + dy*2 + dx] += s;
                }
            }
        }
    }

    // bias, pooled max/min, per-channel stat partials
    float ssum[8], ssq[8];
    size_t obase = ((size_t)n*COUT + co0) * (PD*PD*PD) + ((od << (2*LG)) + (oh << LG) + ow);
    #pragma unroll
    for (int cl = 0; cl < 8; ++cl) {
        float cb = bias[co0 + cl];
        float mx = -1e30f, mn = 1e30f, s = 0.f, q = 0.f;
        #pragma unroll
        for (int p = 0; p < 8; ++p) {
            float val = acc[cl][p] + cb;
            mx = fmaxf(mx, val); mn = fminf(mn, val);
            s += val; q = fmaf(val, val, q);
        }
        ssum[cl] = s; ssq[cl] = q;
        outmax[obase + (size_t)cl*(PD*PD*PD)] = mx;
        outmin[obase + (size_t)cl*(PD*PD*PD)] = mn;
    }

    // wave shuffle-reduce then cross-wave via LDS, one atomic per (block, stat)
    int lane = tid & 63, wid = tid >> 6;
    #pragma unroll
    for (int cl = 0; cl < 8; ++cl) {
        float a_ = ssum[cl], b_ = ssq[cl];
        #pragma unroll
        for (int off = 32; off; off >>= 1) {
            a_ += __shfl_down(a_, off, 64);
            b_ += __shfl_down(b_, off, 64);
        }
        if (lane == 0) { swred[wid*16 + cl*2] = a_; swred[wid*16 + cl*2 + 1] = b_; }
    }
    __syncthreads();
    if (tid < 16) {
        float t = swred[tid] + swred[16 + tid] + swred[32 + tid] + swred[48 + tid];
        unsafeAtomicAdd(&stats[co0*2 + tid], t);
    }
}

__global__ void bn_final_k(const float* __restrict__ stats, const float* __restrict__ g,
                           const float* __restrict__ b, float* __restrict__ sc, float* __restrict__ sh,
                           int C, float invN)
{
    int c = threadIdx.x; if (c >= C) return;
    float m = stats[c*2] * invN;
    float v = stats[c*2+1] * invN - m*m;
    float s = g[c] * rsqrtf(v + 1e-5f);
    sc[c] = s; sh[c] = b[c] - m*s;
}

// out = relu( BN(pooled) ), selecting max if scale>=0 else min (exact pool/BN exchange)
__global__ __launch_bounds__(256) void bn_select_k(
    const float* __restrict__ mx, const float* __restrict__ mn,
    const float* __restrict__ sc, const float* __restrict__ sh,
    float* __restrict__ out, int Cmask, int lgPD3, int total)
{
    int idx = blockIdx.x*256 + threadIdx.x;
    if (idx >= total) return;
    int c = (idx >> lgPD3) & Cmask;
    float s = sc[c];
    float v = (s >= 0.f) ? mx[idx] : mn[idx];
    out[idx] = fmaxf(fmaf(v, s, sh[c]), 0.f);
}

// fc: X[16,32768] @ W[32768,128] -> accumulate into feat[:,384:512]
__global__ __launch_bounds__(128) void fc_acc_k(
    const float* __restrict__ X, const float* __restrict__ W, float* __restrict__ featv)
{
    int t = threadIdx.x;
    int k0 = blockIdx.x*256;
    float acc[16];
    #pragma unroll
    for (int b = 0; b < 16; ++b) acc[b] = 0.f;
    for (int k = k0; k < k0 + 256; ++k) {
        float w = W[(size_t)k*128 + t];
        #pragma unroll
        for (int b = 0; b < 16; ++b) acc[b] = fmaf(X[(size_t)b*32768 + k], w, acc[b]);
    }
    for (int b = 0; b < 16; ++b) unsafeAtomicAdd(featv + b*512 + t, acc[b]);
}

// ---------------- small dense layers ----------------
__global__ __launch_bounds__(256) void head_k(
    const float* __restrict__ X, const float* __restrict__ W, const float* __restrict__ b,
    float* __restrict__ O, int K, int Ncol, int relu)
{
    int t = blockIdx.x*256 + threadIdx.x;
    if (t >= 16*Ncol) return;
    int bi = t / Ncol, c = t % Ncol;
    float acc = b[c];
    for (int k = 0; k < K; ++k) acc = fmaf(X[bi*K + k], W[k*Ncol + c], acc);
    if (relu) acc = fmaxf(acc, 0.f);
    O[bi*Ncol + c] = acc;
}

__global__ void gebn_k(const float* __restrict__ g2, const float* __restrict__ g,
                       const float* __restrict__ b, float* __restrict__ featg /* stride 512 */)
{
    int c = threadIdx.x;  // 128
    float m = 0.f;
    for (int i = 0; i < 16; ++i) m += g2[i*128 + c];
    m *= (1.f/16.f);
    float v = 0.f;
    for (int i = 0; i < 16; ++i) { float d = g2[i*128 + c] - m; v += d*d; }
    v *= (1.f/16.f);
    float s = g[c] * rsqrtf(v + 1e-5f);
    for (int i = 0; i < 16; ++i)
        featg[i*512 + c] = fmaxf((g2[i*128 + c] - m)*s + b[c], 0.f);
}

__global__ void finalize_feat_k(float* __restrict__ feat, const float* __restrict__ cntm,
                                const float* __restrict__ cntz, const float* __restrict__ fcb)
{
    int t = blockIdx.x*256 + threadIdx.x;   // 16*512
    if (t >= 8192) return;
    int bi = t >> 9, c = t & 511;
    float v = feat[t];
    if      (c < 128) v /= fmaxf(cntm[bi], 1.f);
    else if (c < 256) v /= fmaxf(cntz[bi], 1.f);
    else if (c >= 384) v = fmaxf(v + fcb[c - 384], 0.f);
    feat[t] = v;
}

// =====================================================================================
extern "C" void kernel_launch(void* const* d_in, const int* in_sizes, int n_in,
                              void* d_out, int out_size, void* d_ws, size_t ws_size,
                              hipStream_t stream)
{
    const int*   mol_x  = (const int*)  d_in[0];
    const float* mol_q  = (const float*)d_in[1];
    const int*   mol_ei = (const int*)  d_in[2];
    const float* mol_ew = (const float*)d_in[3];
    const int*   mol_bv = (const int*)  d_in[4];
    const int*   zeo_x  = (const int*)  d_in[5];
    const int*   zeo_ei = (const int*)  d_in[6];
    const int*   zeo_bv = (const int*)  d_in[7];
    const float* voxel  = (const float*)d_in[8];
    const float* gattr  = (const float*)d_in[9];
    const float* ea  = (const float*)d_in[10];
    const float* ed  = (const float*)d_in[11];
    const float* ec  = (const float*)d_in[12];
    const float* eh  = (const float*)d_in[13];
    const float* ear = (const float*)d_in[14];
    const float* ech = (const float*)d_in[15];
    const float* mc1w=(const float*)d_in[16]; const float* mc1b=(const float*)d_in[17];
    const float* mc2w=(const float*)d_in[18]; const float* mc2b=(const float*)d_in[19];
    const float* zc1w=(const float*)d_in[20]; const float* zc1b=(const float*)d_in[21];
    const float* zc2w=(const float*)d_in[22]; const float* zc2b=(const float*)d_in[23];
    const float* cv1w=(const float*)d_in[24]; const float* cv1b=(const float*)d_in[25];
    const float* bn1g=(const float*)d_in[26]; const float* bn1b=(const float*)d_in[27];
    const float* cv2w=(const float*)d_in[28]; const float* cv2b=(const float*)d_in[29];
    const float* bn2g=(const float*)d_in[30]; const float* bn2b=(const float*)d_in[31];
    const float* cv3w=(const float*)d_in[32]; const float* cv3b=(const float*)d_in[33];
    const float* bn3g=(const float*)d_in[34]; const float* bn3b=(const float*)d_in[35];
    const float* fcw =(const float*)d_in[36]; const float* fcb =(const float*)d_in[37];
    const float* ge1w=(const float*)d_in[38]; const float* ge1b=(const float*)d_in[39];
    const float* ge2w=(const float*)d_in[40]; const float* ge2b=(const float*)d_in[41];
    const float* gbng=(const float*)d_in[42]; const float* gbnb=(const float*)d_in[43];
    const float* h1w =(const float*)d_in[44]; const float* h1b =(const float*)d_in[45];
    const float* h2w =(const float*)d_in[46]; const float* h2b =(const float*)d_in[47];
    const float* h3w =(const float*)d_in[48]; const float* h3b =(const float*)d_in[49];

    const int Nm = in_sizes[0]/6, Em = in_sizes[2]/2;
    const int Nz = in_sizes[5]/6, Ez = in_sizes[6]/2;

    float* WS = (float*)d_ws;
    float* A  = WS;                     // 16,777,216 floats (67 MB)
    float* Bb = WS + 16777216;          // 16,777,216 floats (67 MB)
    float* S  = WS + 33554432;          // small scratch
    float* deg  = S;
    float* dis  = S + 131072;
    float* nrm  = S + 262144;
    float* T    = S + 786432;           // 161*128
    float* cntm = S + 807040;
    float* cntz = S + 807056;
    float* feat = S + 807072;           // [16][512]
    float* st1  = S + 815264; float* st2 = st1 + 32; float* st3 = st1 + 96;
    float* sc1  = S + 815488; float* sh1 = sc1 + 16;
    float* sc2  = sc1 + 32;   float* sh2 = sc1 + 64;
    float* sc3  = sc1 + 96;   float* sh3 = sc1 + 160;
    float* g1   = S + 815712;           // 16*64
    float* g2   = S + 816736;           // 16*128
    float* H1   = S + 818784;           // 16*512
    float* H2   = S + 826976;           // 16*256

    // zero all small accumulators (graph re-zeroes each replay)
    hipMemsetAsync(S, 0, (size_t)831072*sizeof(float), stream);

    // ---------------- molecule branch ----------------
    build_tables_k<<<161,128,0,stream>>>(ea,ed,ec,eh,ear,ech, mc1w, T);
    init_deg_k   <<<Nm/256,256,0,stream>>>(deg, Nm);
    deg_scatter_k<<<Em/256,256,0,stream>>>(mol_ei+Em, mol_ew, deg, Em);
    dis_k        <<<Nm/256,256,0,stream>>>(deg, dis, Nm);
    norm_k       <<<Em/256,256,0,stream>>>(mol_ei, mol_ei+Em, mol_ew, dis, nrm, Em);
    embed_lookup_k<<<Nm/8,256,0,stream>>>(mol_x, mol_q, T, mc1w + 112*128, A, Nm);
    self_init_k  <<<Nm/8,256,0,stream>>>(A, dis, mc1b, Bb, Nm);
    gcn_scatter_k<<<Em/4,256,0,stream>>>(A, mol_ei, mol_ei+Em, nrm, Bb, Em);
    gemm_relu128_k<<<Nm/128,256,0,stream>>>(Bb, mc2w, A, Nm);
    self_init_k  <<<Nm/8,256,0,stream>>>(A, dis, mc2b, Bb, Nm);
    gcn_scatter_k<<<Em/4,256,0,stream>>>(A, mol_ei, mol_ei+Em, nrm, Bb, Em);
    count_batch_k<<<Nm/256,256,0,stream>>>(mol_bv, cntm, Nm);
    mean_pool_sum_k<<<256,128,0,stream>>>(Bb, mol_bv, feat + 0, (Nm+255)/256, Nm);

    // ---------------- zeolite branch ----------------
    build_tables_k<<<161,128,0,stream>>>(ea,ed,ec,eh,ear,ech, zc1w, T);
    init_deg_k   <<<Nz/256,256,0,stream>>>(deg, Nz);
    deg_scatter_k<<<Ez/256,256,0,stream>>>(zeo_ei+Ez, nullptr, deg, Ez);
    dis_k        <<<Nz/256,256,0,stream>>>(deg, dis, Nz);
    norm_k       <<<Ez/256,256,0,stream>>>(zeo_ei, zeo_ei+Ez, nullptr, dis, nrm, Ez);
    embed_lookup_k<<<Nz/8,256,0,stream>>>(zeo_x, nullptr, T, nullptr, A, Nz);
    self_init_k  <<<Nz/8,256,0,stream>>>(A, dis, zc1b, Bb, Nz);
    gcn_scatter_k<<<Ez/4,256,0,stream>>>(A, zeo_ei, zeo_ei+Ez, nrm, Bb, Ez);
    gemm_relu128_k<<<Nz/128,256,0,stream>>>(Bb, zc2w, A, Nz);
    self_init_k  <<<Nz/8,256,0,stream>>>(A, dis, zc2b, Bb, Nz);
    gcn_scatter_k<<<Ez/4,256,0,stream>>>(A, zeo_ei, zeo_ei+Ez, nrm, Bb, Ez);
    count_batch_k<<<Nz/256,256,0,stream>>>(zeo_bv, cntz, Nz);
    mean_pool_sum_k<<<256,128,0,stream>>>(Bb, zeo_bv, feat + 128, (Nz+255)/256, Nz);

    // ---------------- voxel CNN (fused conv+bias+stats+pool, then BN-select) ----------------
    // layer 1: voxel [16][2][64^3] -> pooled max/min in A (2 x 8.4M floats)
    conv_pool_k<2,16,64><<<dim3(2048,2),256,0,stream>>>(voxel, cv1w, cv1b, A, A+8388608, st1);
    bn_final_k<<<1,64,0,stream>>>(st1, bn1g, bn1b, sc1, sh1, 16, 1.f/(16.f*262144.f));
    bn_select_k<<<32768,256,0,stream>>>(A, A+8388608, sc1, sh1, Bb, 15, 15, 8388608);

    // layer 2: Bb [16][16][32^3] -> pooled max/min in A (2 x 2.1M floats)
    conv_pool_k<16,32,32><<<dim3(256,4),256,0,stream>>>(Bb, cv2w, cv2b, A, A+2097152, st2);
    bn_final_k<<<1,64,0,stream>>>(st2, bn2g, bn2b, sc2, sh2, 32, 1.f/(16.f*32768.f));
    bn_select_k<<<8192,256,0,stream>>>(A, A+2097152, sc2, sh2, Bb, 31, 12, 2097152);

    // layer 3: Bb [16][32][16^3] -> pooled max/min in A (2 x 524288 floats)
    conv_pool_k<32,64,16><<<dim3(32,8),256,0,stream>>>(Bb, cv3w, cv3b, A, A+524288, st3);
    bn_final_k<<<1,64,0,stream>>>(st3, bn3g, bn3b, sc3, sh3, 64, 1.f/(16.f*4096.f));
    bn_select_k<<<2048,256,0,stream>>>(A, A+524288, sc3, sh3, Bb, 63, 9, 524288);

    fc_acc_k<<<128,128,0,stream>>>(Bb, fcw, feat + 384);

    // ---------------- global encoder ----------------
    head_k<<<4,256,0,stream>>>(gattr, ge1w, ge1b, g1, 17, 64, 1);
    head_k<<<8,256,0,stream>>>(g1, ge2w, ge2b, g2, 64, 128, 0);
    gebn_k<<<1,128,0,stream>>>(g2, gbng, gbnb, feat + 256);

    // ---------------- fusion head ----------------
    finalize_feat_k<<<32,256,0,stream>>>(feat, cntm, cntz, fcb);
    head_k<<<32,256,0,stream>>>(feat, h1w, h1b, H1, 512, 512, 1);
    head_k<<<16,256,0,stream>>>(H1, h2w, h2b, H2, 512, 256, 1);
    head_k<<<1,256,0,stream>>>(H2, h3w, h3b, (float*)d_out, 256, 3, 0);
}

// Round 4
// 2706.868 us; speedup vs baseline: 2.3734x; 1.2937x over previous
//
#include <hip/hip_runtime.h>
#include <math.h>

#define DEV static __device__ __forceinline__

DEV float4 ld4(const float* p){ return *(const float4*)p; }
DEV void   st4(float* p, float4 v){ *(float4*)p = v; }
DEV float4 f4add(float4 a, float4 b){ return make_float4(a.x+b.x,a.y+b.y,a.z+b.z,a.w+b.w); }
DEV float4 f4fma(float s, float4 a, float4 c){ return make_float4(fmaf(s,a.x,c.x),fmaf(s,a.y,c.y),fmaf(s,a.z,c.z),fmaf(s,a.w,c.w)); }
DEV float4 f4relu(float4 a){ return make_float4(fmaxf(a.x,0.f),fmaxf(a.y,0.f),fmaxf(a.z,0.f),fmaxf(a.w,0.f)); }

// ---------------- GNN: embedding tables  T[161][128] = emb_f @ W_slice ----------------
__global__ __launch_bounds__(128) void build_tables_k(
    const float* __restrict__ ea, const float* __restrict__ ed, const float* __restrict__ ec,
    const float* __restrict__ eh, const float* __restrict__ ear, const float* __restrict__ ech,
    const float* __restrict__ Wm, float* __restrict__ T)
{
    int r = blockIdx.x, c = threadIdx.x;
    const float* e; int dim, woff, rl;
    if      (r < 120) { e=ea;  dim=64; woff=0;   rl=r; }
    else if (r < 132) { e=ed;  dim=16; woff=64;  rl=r-120; }
    else if (r < 147) { e=ec;  dim=16; woff=80;  rl=r-132; }
    else if (r < 155) { e=eh;  dim=8;  woff=96;  rl=r-147; }
    else if (r < 157) { e=ear; dim=4;  woff=104; rl=r-155; }
    else              { e=ech; dim=4;  woff=108; rl=r-157; }
    float acc = 0.f;
    for (int k = 0; k < dim; ++k) acc += e[rl*dim + k] * Wm[(woff + k)*128 + c];
    T[r*128 + c] = acc;
}

// H[i][:] = sum of 6 table rows (+ charge * Wrow112)
__global__ __launch_bounds__(256) void embed_lookup_k(
    const int* __restrict__ xi, const float* __restrict__ charge,
    const float* __restrict__ T, const float* __restrict__ wq,
    float* __restrict__ H, int N)
{
    int t = threadIdx.x;
    int node = blockIdx.x*8 + (t >> 5);
    if (node >= N) return;
    int c = (t & 31)*4;
    const int* xp = xi + node*6;
    float4 acc = ld4(T + (       xp[0])*128 + c);
    acc = f4add(acc, ld4(T + (120+xp[1])*128 + c));
    acc = f4add(acc, ld4(T + (132+xp[2])*128 + c));
    acc = f4add(acc, ld4(T + (147+xp[3])*128 + c));
    acc = f4add(acc, ld4(T + (155+xp[4])*128 + c));
    acc = f4add(acc, ld4(T + (157+xp[5])*128 + c));
    if (charge) acc = f4fma(charge[node], ld4(wq + c), acc);
    st4(H + (size_t)node*128 + c, acc);
}

// ---------------- GCN degree / norm / CSR build ----------------
__global__ void init_deg_k(float* deg, int N){ int i = blockIdx.x*256+threadIdx.x; if (i<N) deg[i]=1.f; }

__global__ void deg_scatter_k(const int* __restrict__ col, const float* __restrict__ ew, float* deg, int E){
    int e = blockIdx.x*256+threadIdx.x; if (e>=E) return;
    unsafeAtomicAdd(deg + col[e], ew ? ew[e] : 1.f);
}

__global__ void dis_k(const float* __restrict__ deg, float* __restrict__ dis, int N){
    int i = blockIdx.x*256+threadIdx.x; if (i<N) dis[i] = 1.f/sqrtf(deg[i]);
}

// integer in-degree count (into cursor buffer, pre-zeroed)
__global__ void count_in_k(const int* __restrict__ col, int* __restrict__ cnt, int E){
    int e = blockIdx.x*256+threadIdx.x; if (e>=E) return;
    atomicAdd(&cnt[col[e]], 1);
}

// single-block exclusive scan: cnt (in cursor) -> rowptr; cursor reset to starts
__global__ __launch_bounds__(1024) void scan_k(int* __restrict__ cnt_cursor, int* __restrict__ rowptr, int N)
{
    __shared__ int part[1024];
    int t = threadIdx.x;
    int chunk = (N + 1023) >> 10;
    int base = t*chunk;
    int s = 0;
    for (int i = 0; i < chunk; ++i) { int idx = base+i; if (idx < N) s += cnt_cursor[idx]; }
    part[t] = s;
    __syncthreads();
    for (int off = 1; off < 1024; off <<= 1) {
        int v = (t >= off) ? part[t-off] : 0;
        __syncthreads();
        if (t >= off) part[t] += v;
        __syncthreads();
    }
    int run = (t == 0) ? 0 : part[t-1];
    for (int i = 0; i < chunk; ++i) {
        int idx = base+i; if (idx >= N) break;
        int c = cnt_cursor[idx];
        rowptr[idx] = run;
        cnt_cursor[idx] = run;   // cursor = start
        run += c;
    }
    if (t == 1023) rowptr[N] = part[1023];
}

// scatter edges into CSR slots; norm computed inline
__global__ void fill_csr_k(const int* __restrict__ row, const int* __restrict__ col,
                           const float* __restrict__ ew, const float* __restrict__ dis,
                           int* __restrict__ cursor, int* __restrict__ csr_src,
                           float* __restrict__ csr_nrm, int E)
{
    int e = blockIdx.x*256+threadIdx.x; if (e>=E) return;
    int r = row[e], c = col[e];
    int pos = atomicAdd(&cursor[c], 1);
    csr_src[pos] = r;
    csr_nrm[pos] = dis[r] * (ew ? ew[e] : 1.f) * dis[c];
}

// O[i] = bias + dis[i]^2 * H[i] + sum_j nrm_j * H[src_j]   (one wave per node, no atomics)
__global__ __launch_bounds__(256) void gcn_gather_k(
    const float* __restrict__ H, const int* __restrict__ rowptr,
    const int* __restrict__ csr_src, const float* __restrict__ csr_nrm,
    const float* __restrict__ dis, const float* __restrict__ bias,
    float* __restrict__ O, int N)
{
    int node = blockIdx.x*4 + (threadIdx.x >> 6);
    if (node >= N) return;
    int lane = threadIdx.x & 63;
    float s = dis[node]; s *= s;
    float2 h = *(const float2*)(H + (size_t)node*128 + lane*2);
    float2 b = *(const float2*)(bias + lane*2);
    float2 acc = make_float2(fmaf(s, h.x, b.x), fmaf(s, h.y, b.y));
    int beg = rowptr[node], end = rowptr[node+1];
    for (int j = beg; j < end; ++j) {
        int src = csr_src[j];
        float nm = csr_nrm[j];
        float2 hv = *(const float2*)(H + (size_t)src*128 + lane*2);
        acc.x = fmaf(nm, hv.x, acc.x);
        acc.y = fmaf(nm, hv.y, acc.y);
    }
    *(float2*)(O + (size_t)node*128 + lane*2) = acc;
}

// O = relu(A) @ W ; A:[N,128] W:[128,128]
__global__ __launch_bounds__(256) void gemm_relu128_k(
    const float* __restrict__ A, const float* __restrict__ W, float* __restrict__ O, int N)
{
    __shared__ float As[128*128];
    int t = threadIdx.x;
    int row0 = blockIdx.x * 128;
    int r = t >> 1, c0 = (t & 1)*64;
    for (int i = 0; i < 16; ++i) {
        float4 v = ld4(A + (size_t)(row0 + r)*128 + c0 + i*4);
        st4(As + r*128 + c0 + i*4, f4relu(v));
    }
    __syncthreads();
    int rg = (t >> 5)*16;
    int c  = (t & 31)*4;
    float4 acc[16];
    for (int i = 0; i < 16; ++i) acc[i] = make_float4(0.f,0.f,0.f,0.f);
    for (int k = 0; k < 128; ++k) {
        float4 w = ld4(W + k*128 + c);
        #pragma unroll
        for (int rr = 0; rr < 16; ++rr) {
            float a = As[(rg + rr)*128 + k];
            acc[rr] = f4fma(a, w, acc[rr]);
        }
    }
    for (int rr = 0; rr < 16; ++rr)
        st4(O + (size_t)(row0 + rg + rr)*128 + c, acc[rr]);
}

// ---------------- mean pool ----------------
__global__ __launch_bounds__(128) void mean_pool_sum_k(
    const float* __restrict__ X, const int* __restrict__ bv,
    float* __restrict__ featp /* stride 512 */, int chunk, int N)
{
    __shared__ float acc[16*128];
    int t = threadIdx.x;
    for (int b = 0; b < 16; ++b) acc[b*128 + t] = 0.f;
    int i0 = blockIdx.x * chunk;
    int iend = min(i0 + chunk, N);
    int bcur = bv[i0];
    float r = 0.f;
    for (int i = i0; i < iend; ++i) {
        int b = bv[i];
        if (b != bcur) { acc[bcur*128 + t] += r; r = 0.f; bcur = b; }
        r += fmaxf(X[(size_t)i*128 + t], 0.f);
    }
    acc[bcur*128 + t] += r;
    for (int b = 0; b < 16; ++b) {
        float v = acc[b*128 + t];
        if (v != 0.f) unsafeAtomicAdd(featp + b*512 + t, v);
    }
}

__global__ void count_batch_k(const int* __restrict__ bv, float* __restrict__ cnt, int N){
    __shared__ int h[16];
    int t = threadIdx.x;
    if (t < 16) h[t] = 0;
    __syncthreads();
    int i = blockIdx.x*256 + t;
    if (i < N) atomicAdd(&h[bv[i]], 1);
    __syncthreads();
    if (t < 16 && h[t]) unsafeAtomicAdd(&cnt[t], (float)h[t]);
}

// ---------------- voxel CNN: fused conv(3x3x3 SAME) + bias + BN-stats + maxpool/minpool ----------------
template<int CIN, int COUT, int D>
__global__ __launch_bounds__(256) void conv_pool_k(
    const float* __restrict__ in, const float* __restrict__ wt, const float* __restrict__ bias,
    float* __restrict__ outmax, float* __restrict__ outmin, float* __restrict__ stats)
{
    constexpr int PD = D/2;
    constexpr int LG = (PD == 32) ? 5 : (PD == 16 ? 4 : 3);
    __shared__ float ldsW[CIN*9*32];
    __shared__ float swred[4*16];

    int tid = threadIdx.x;
    int co0 = blockIdx.y * 8;

    for (int i = tid; i < CIN*9*32; i += 256) {
        int kw = i & 3, cl = (i >> 2) & 7, r = (i >> 5) % 9, ci = i / 288;
        ldsW[i] = (kw < 3) ? wt[((co0 + cl)*CIN + ci)*27 + r*3 + kw] : 0.f;
    }
    __syncthreads();

    int idx = blockIdx.x*256 + tid;
    int ow = idx & (PD-1);
    int oh = (idx >> LG) & (PD-1);
    int od = (idx >> (2*LG)) & (PD-1);
    int n  = idx >> (3*LG);

    float acc[8][8];
    #pragma unroll
    for (int cl = 0; cl < 8; ++cl)
        #pragma unroll
        for (int p = 0; p < 8; ++p) acc[cl][p] = 0.f;

    int z0 = (od << 1) - 1, y0 = (oh << 1) - 1, x0 = (ow << 1) - 1;

    for (int ci = 0; ci < CIN; ++ci) {
        const float* ib = in + ((size_t)n*CIN + ci)*((size_t)D*D*D);
        float v[4][4][4];
        #pragma unroll
        for (int a = 0; a < 4; ++a) {
            int z = z0 + a; bool zok = (unsigned)z < (unsigned)D;
            #pragma unroll
            for (int b = 0; b < 4; ++b) {
                int y = y0 + b; bool yok = zok && ((unsigned)y < (unsigned)D);
                const float* rp = ib + ((size_t)z*D + y)*D;
                #pragma unroll
                for (int c = 0; c < 4; ++c) {
                    int x = x0 + c;
                    v[a][b][c] = (yok && (unsigned)x < (unsigned)D) ? rp[x] : 0.f;
                }
            }
        }
        const float4* wrow = (const float4*)ldsW + ci*9*8;
        #pragma unroll
        for (int r = 0; r < 9; ++r) {
            const int kd = r/3, kh = r%3;
            #pragma unroll
            for (int cl = 0; cl < 8; ++cl) {
                float4 w = wrow[r*8 + cl];
                #pragma unroll
                for (int dz = 0; dz < 2; ++dz)
                #pragma unroll
                for (int dy = 0; dy < 2; ++dy)
                #pragma unroll
                for (int dx = 0; dx < 2; ++dx) {
                    float s = fmaf(w.x, v[dz+kd][dy+kh][dx],
                              fmaf(w.y, v[dz+kd][dy+kh][dx+1],
                                   w.z * v[dz+kd][dy+kh][dx+2]));
                    acc[cl][dz*4 + dy*2 + dx] += s;
                }
            }
        }
    }

    float ssum[8], ssq[8];
    size_t obase = ((size_t)n*COUT + co0) * (PD*PD*PD) + ((od << (2*LG)) + (oh << LG) + ow);
    #pragma unroll
    for (int cl = 0; cl < 8; ++cl) {
        float cb = bias[co0 + cl];
        float mx = -1e30f, mn = 1e30f, s = 0.f, q = 0.f;
        #pragma unroll
        for (int p = 0; p < 8; ++p) {
            float val = acc[cl][p] + cb;
            mx = fmaxf(mx, val); mn = fminf(mn, val);
            s += val; q = fmaf(val, val, q);
        }
        ssum[cl] = s; ssq[cl] = q;
        outmax[obase + (size_t)cl*(PD*PD*PD)] = mx;
        outmin[obase + (size_t)cl*(PD*PD*PD)] = mn;
    }

    int lane = tid & 63, wid = tid >> 6;
    #pragma unroll
    for (int cl = 0; cl < 8; ++cl) {
        float a_ = ssum[cl], b_ = ssq[cl];
        #pragma unroll
        for (int off = 32; off; off >>= 1) {
            a_ += __shfl_down(a_, off, 64);
            b_ += __shfl_down(b_, off, 64);
        }
        if (lane == 0) { swred[wid*16 + cl*2] = a_; swred[wid*16 + cl*2 + 1] = b_; }
    }
    __syncthreads();
    if (tid < 16) {
        float t = swred[tid] + swred[16 + tid] + swred[32 + tid] + swred[48 + tid];
        unsafeAtomicAdd(&stats[co0*2 + tid], t);
    }
}

__global__ void bn_final_k(const float* __restrict__ stats, const float* __restrict__ g,
                           const float* __restrict__ b, float* __restrict__ sc, float* __restrict__ sh,
                           int C, float invN)
{
    int c = threadIdx.x; if (c >= C) return;
    float m = stats[c*2] * invN;
    float v = stats[c*2+1] * invN - m*m;
    float s = g[c] * rsqrtf(v + 1e-5f);
    sc[c] = s; sh[c] = b[c] - m*s;
}

__global__ __launch_bounds__(256) void bn_select_k(
    const float* __restrict__ mx, const float* __restrict__ mn,
    const float* __restrict__ sc, const float* __restrict__ sh,
    float* __restrict__ out, int Cmask, int lgPD3, int total)
{
    int idx = blockIdx.x*256 + threadIdx.x;
    if (idx >= total) return;
    int c = (idx >> lgPD3) & Cmask;
    float s = sc[c];
    float v = (s >= 0.f) ? mx[idx] : mn[idx];
    out[idx] = fmaxf(fmaf(v, s, sh[c]), 0.f);
}

// fc: X[16,32768] @ W[32768,128] -> accumulate into feat[:,384:512]
__global__ __launch_bounds__(128) void fc_acc_k(
    const float* __restrict__ X, const float* __restrict__ W, float* __restrict__ featv)
{
    int t = threadIdx.x;
    int k0 = blockIdx.x*256;
    float acc[16];
    #pragma unroll
    for (int b = 0; b < 16; ++b) acc[b] = 0.f;
    for (int k = k0; k < k0 + 256; ++k) {
        float w = W[(size_t)k*128 + t];
        #pragma unroll
        for (int b = 0; b < 16; ++b) acc[b] = fmaf(X[(size_t)b*32768 + k], w, acc[b]);
    }
    for (int b = 0; b < 16; ++b) unsafeAtomicAdd(featv + b*512 + t, acc[b]);
}

// ---------------- small dense layers ----------------
__global__ __launch_bounds__(256) void head_k(
    const float* __restrict__ X, const float* __restrict__ W, const float* __restrict__ b,
    float* __restrict__ O, int K, int Ncol, int relu)
{
    int t = blockIdx.x*256 + threadIdx.x;
    if (t >= 16*Ncol) return;
    int bi = t / Ncol, c = t % Ncol;
    float acc = b[c];
    for (int k = 0; k < K; ++k) acc = fmaf(X[bi*K + k], W[k*Ncol + c], acc);
    if (relu) acc = fmaxf(acc, 0.f);
    O[bi*Ncol + c] = acc;
}

__global__ void gebn_k(const float* __restrict__ g2, const float* __restrict__ g,
                       const float* __restrict__ b, float* __restrict__ featg /* stride 512 */)
{
    int c = threadIdx.x;  // 128
    float m = 0.f;
    for (int i = 0; i < 16; ++i) m += g2[i*128 + c];
    m *= (1.f/16.f);
    float v = 0.f;
    for (int i = 0; i < 16; ++i) { float d = g2[i*128 + c] - m; v += d*d; }
    v *= (1.f/16.f);
    float s = g[c] * rsqrtf(v + 1e-5f);
    for (int i = 0; i < 16; ++i)
        featg[i*512 + c] = fmaxf((g2[i*128 + c] - m)*s + b[c], 0.f);
}

__global__ void finalize_feat_k(float* __restrict__ feat, const float* __restrict__ cntm,
                                const float* __restrict__ cntz, const float* __restrict__ fcb)
{
    int t = blockIdx.x*256 + threadIdx.x;   // 16*512
    if (t >= 8192) return;
    int bi = t >> 9, c = t & 511;
    float v = feat[t];
    if      (c < 128) v /= fmaxf(cntm[bi], 1.f);
    else if (c < 256) v /= fmaxf(cntz[bi], 1.f);
    else if (c >= 384) v = fmaxf(v + fcb[c - 384], 0.f);
    feat[t] = v;
}

// =====================================================================================
extern "C" void kernel_launch(void* const* d_in, const int* in_sizes, int n_in,
                              void* d_out, int out_size, void* d_ws, size_t ws_size,
                              hipStream_t stream)
{
    const int*   mol_x  = (const int*)  d_in[0];
    const float* mol_q  = (const float*)d_in[1];
    const int*   mol_ei = (const int*)  d_in[2];
    const float* mol_ew = (const float*)d_in[3];
    const int*   mol_bv = (const int*)  d_in[4];
    const int*   zeo_x  = (const int*)  d_in[5];
    const int*   zeo_ei = (const int*)  d_in[6];
    const int*   zeo_bv = (const int*)  d_in[7];
    const float* voxel  = (const float*)d_in[8];
    const float* gattr  = (const float*)d_in[9];
    const float* ea  = (const float*)d_in[10];
    const float* ed  = (const float*)d_in[11];
    const float* ec  = (const float*)d_in[12];
    const float* eh  = (const float*)d_in[13];
    const float* ear = (const float*)d_in[14];
    const float* ech = (const float*)d_in[15];
    const float* mc1w=(const float*)d_in[16]; const float* mc1b=(const float*)d_in[17];
    const float* mc2w=(const float*)d_in[18]; const float* mc2b=(const float*)d_in[19];
    const float* zc1w=(const float*)d_in[20]; const float* zc1b=(const float*)d_in[21];
    const float* zc2w=(const float*)d_in[22]; const float* zc2b=(const float*)d_in[23];
    const float* cv1w=(const float*)d_in[24]; const float* cv1b=(const float*)d_in[25];
    const float* bn1g=(const float*)d_in[26]; const float* bn1b=(const float*)d_in[27];
    const float* cv2w=(const float*)d_in[28]; const float* cv2b=(const float*)d_in[29];
    const float* bn2g=(const float*)d_in[30]; const float* bn2b=(const float*)d_in[31];
    const float* cv3w=(const float*)d_in[32]; const float* cv3b=(const float*)d_in[33];
    const float* bn3g=(const float*)d_in[34]; const float* bn3b=(const float*)d_in[35];
    const float* fcw =(const float*)d_in[36]; const float* fcb =(const float*)d_in[37];
    const float* ge1w=(const float*)d_in[38]; const float* ge1b=(const float*)d_in[39];
    const float* ge2w=(const float*)d_in[40]; const float* ge2b=(const float*)d_in[41];
    const float* gbng=(const float*)d_in[42]; const float* gbnb=(const float*)d_in[43];
    const float* h1w =(const float*)d_in[44]; const float* h1b =(const float*)d_in[45];
    const float* h2w =(const float*)d_in[46]; const float* h2b =(const float*)d_in[47];
    const float* h3w =(const float*)d_in[48]; const float* h3b =(const float*)d_in[49];

    const int Nm = in_sizes[0]/6, Em = in_sizes[2]/2;
    const int Nz = in_sizes[5]/6, Ez = in_sizes[6]/2;

    float* WS = (float*)d_ws;
    float* A  = WS;                     // 16,777,216 floats (67 MB)
    float* Bb = WS + 16777216;          // 16,777,216 floats (67 MB)
    float* S  = WS + 33554432;          // small scratch
    float* deg  = S;
    float* dis  = S + 131072;
    float* csr_nrm = S + 262144;        // 524288
    float* T    = S + 786432;           // 161*128
    float* cntm = S + 807040;
    float* cntz = S + 807056;
    float* feat = S + 807072;           // [16][512]
    float* st1  = S + 815264; float* st2 = st1 + 32; float* st3 = st1 + 96;
    float* sc1  = S + 815488; float* sh1 = sc1 + 16;
    float* sc2  = sc1 + 32;   float* sh2 = sc1 + 64;
    float* sc3  = sc1 + 96;   float* sh3 = sc1 + 160;
    float* g1   = S + 815712;           // 16*64
    float* g2   = S + 816736;           // 16*128
    float* H1   = S + 818784;           // 16*512
    float* H2   = S + 826976;           // 16*256
    int* rowptr  = (int*)(S + 831072);  // 131073
    int* cursor  = (int*)(S + 962176);  // 131072
    int* csr_src = (int*)(S + 1093248); // 524288  (ends S+1617536)

    // zero small accumulators (feat/stats/cnt) each replay
    hipMemsetAsync(S, 0, (size_t)831072*sizeof(float), stream);

    // ---------------- molecule branch ----------------
    build_tables_k<<<161,128,0,stream>>>(ea,ed,ec,eh,ear,ech, mc1w, T);
    init_deg_k   <<<Nm/256,256,0,stream>>>(deg, Nm);
    deg_scatter_k<<<Em/256,256,0,stream>>>(mol_ei+Em, mol_ew, deg, Em);
    dis_k        <<<Nm/256,256,0,stream>>>(deg, dis, Nm);
    hipMemsetAsync(cursor, 0, (size_t)Nm*sizeof(int), stream);
    count_in_k   <<<Em/256,256,0,stream>>>(mol_ei+Em, cursor, Em);
    scan_k       <<<1,1024,0,stream>>>(cursor, rowptr, Nm);
    fill_csr_k   <<<Em/256,256,0,stream>>>(mol_ei, mol_ei+Em, mol_ew, dis, cursor, csr_src, csr_nrm, Em);
    embed_lookup_k<<<Nm/8,256,0,stream>>>(mol_x, mol_q, T, mc1w + 112*128, A, Nm);
    gcn_gather_k <<<Nm/4,256,0,stream>>>(A, rowptr, csr_src, csr_nrm, dis, mc1b, Bb, Nm);
    gemm_relu128_k<<<Nm/128,256,0,stream>>>(Bb, mc2w, A, Nm);
    gcn_gather_k <<<Nm/4,256,0,stream>>>(A, rowptr, csr_src, csr_nrm, dis, mc2b, Bb, Nm);
    count_batch_k<<<Nm/256,256,0,stream>>>(mol_bv, cntm, Nm);
    mean_pool_sum_k<<<256,128,0,stream>>>(Bb, mol_bv, feat + 0, (Nm+255)/256, Nm);

    // ---------------- zeolite branch ----------------
    build_tables_k<<<161,128,0,stream>>>(ea,ed,ec,eh,ear,ech, zc1w, T);
    init_deg_k   <<<Nz/256,256,0,stream>>>(deg, Nz);
    deg_scatter_k<<<Ez/256,256,0,stream>>>(zeo_ei+Ez, nullptr, deg, Ez);
    dis_k        <<<Nz/256,256,0,stream>>>(deg, dis, Nz);
    hipMemsetAsync(cursor, 0, (size_t)Nz*sizeof(int), stream);
    count_in_k   <<<Ez/256,256,0,stream>>>(zeo_ei+Ez, cursor, Ez);
    scan_k       <<<1,1024,0,stream>>>(cursor, rowptr, Nz);
    fill_csr_k   <<<Ez/256,256,0,stream>>>(zeo_ei, zeo_ei+Ez, nullptr, dis, cursor, csr_src, csr_nrm, Ez);
    embed_lookup_k<<<Nz/8,256,0,stream>>>(zeo_x, nullptr, T, nullptr, A, Nz);
    gcn_gather_k <<<Nz/4,256,0,stream>>>(A, rowptr, csr_src, csr_nrm, dis, zc1b, Bb, Nz);
    gemm_relu128_k<<<Nz/128,256,0,stream>>>(Bb, zc2w, A, Nz);
    gcn_gather_k <<<Nz/4,256,0,stream>>>(A, rowptr, csr_src, csr_nrm, dis, zc2b, Bb, Nz);
    count_batch_k<<<Nz/256,256,0,stream>>>(zeo_bv, cntz, Nz);
    mean_pool_sum_k<<<256,128,0,stream>>>(Bb, zeo_bv, feat + 128, (Nz+255)/256, Nz);

    // ---------------- voxel CNN (fused conv+bias+stats+pool, then BN-select) ----------------
    conv_pool_k<2,16,64><<<dim3(2048,2),256,0,stream>>>(voxel, cv1w, cv1b, A, A+8388608, st1);
    bn_final_k<<<1,64,0,stream>>>(st1, bn1g, bn1b, sc1, sh1, 16, 1.f/(16.f*262144.f));
    bn_select_k<<<32768,256,0,stream>>>(A, A+8388608, sc1, sh1, Bb, 15, 15, 8388608);

    conv_pool_k<16,32,32><<<dim3(256,4),256,0,stream>>>(Bb, cv2w, cv2b, A, A+2097152, st2);
    bn_final_k<<<1,64,0,stream>>>(st2, bn2g, bn2b, sc2, sh2, 32, 1.f/(16.f*32768.f));
    bn_select_k<<<8192,256,0,stream>>>(A, A+2097152, sc2, sh2, Bb, 31, 12, 2097152);

    conv_pool_k<32,64,16><<<dim3(32,8),256,0,stream>>>(Bb, cv3w, cv3b, A, A+524288, st3);
    bn_final_k<<<1,64,0,stream>>>(st3, bn3g, bn3b, sc3, sh3, 64, 1.f/(16.f*4096.f));
    bn_select_k<<<2048,256,0,stream>>>(A, A+524288, sc3, sh3, Bb, 63, 9, 524288);

    fc_acc_k<<<128,128,0,stream>>>(Bb, fcw, feat + 384);

    // ---------------- global encoder ----------------
    head_k<<<4,256,0,stream>>>(gattr, ge1w, ge1b, g1, 17, 64, 1);
    head_k<<<8,256,0,stream>>>(g1, ge2w, ge2b, g2, 64, 128, 0);
    gebn_k<<<1,128,0,stream>>>(g2, gbng, gbnb, feat + 256);

    // ---------------- fusion head ----------------
    finalize_feat_k<<<32,256,0,stream>>>(feat, cntm, cntz, fcb);
    head_k<<<32,256,0,stream>>>(feat, h1w, h1b, H1, 512, 512, 1);
    head_k<<<16,256,0,stream>>>(H1, h2w, h2b, H2, 512, 256, 1);
    head_k<<<1,256,0,stream>>>(H2, h3w, h3b, (float*)d_out, 256, 3, 0);
}